// Round 10
// baseline (209.470 us; speedup 1.0000x reference)
//
#include <hip/hip_runtime.h>
#include <hip/hip_fp16.h>

#define NBINS 255
#define NPAIRS 32
#define BIGF 3.0e38f

// ws layout (float index):
//   [0     ,16384) : E    [64][256] fp32, tail BIGF
//   [16384 ,32768) : PE   [64][256]
//   [32768 ,36864) : M4E  (legacy mid tables; written, no longer read)
//   [36864 ,40960) : M4P
//   [40960 ,41984) : CU16 [64][16] coarse e[16j+15], j=15 pad BIGF
//   [41984 ,43008) : CP16
//   [43008 ,51200) : W16g [64][256] fp16 PRE-SHIFTED (8192 floats of storage)
//   byte 204800 .. : T16  [32][256][256] fp16 PRE-SHIFTED (needs ws >= 4399104 B)
//
// v11: 2-level search. coarse t (15 SGPR compares) -> read ALL 16 edges of
// section t as 4 PARALLEL ds_read_b128 -> c = 16t + sum(x>=e[16t+k], k=0..15).
// The k=15 compare is the section boundary: 0 by coarse construction (or BIGF
// pad) -> summing the full set is exact and ORDER-INVARIANT, which lets the
// LDS fine table be stored TRANSPOSED (float4 (f,k,t) at f*64+k*16+t) so the
// 4 reads are 2-way bank-conflicted (free) instead of 8-way. Mid level gone:
// one dependent LDS round-trip per feature per table instead of two.

__global__ void ebm_prep(const float* __restrict__ edges,
                         const float* __restrict__ pair_edges,
                         const float* __restrict__ w,
                         float* __restrict__ ws) {
    int tid = blockIdx.x * blockDim.x + threadIdx.x;  // 16384 threads
    int f = tid >> 8, j = tid & 255;
    float* E  = ws;
    float* PE = ws + 16384;
    float* ME = ws + 32768;
    float* MP = ws + 36864;
    float* CU = ws + 40960;
    float* CP = ws + 41984;
    __half* W = (__half*)(ws + 43008);
    E[tid]  = (j < NBINS) ? edges[f * NBINS + j]      : BIGF;
    PE[tid] = (j < NBINS) ? pair_edges[f * NBINS + j] : BIGF;
    int src = (j < 255) ? j + 1 : 0;
    W[tid]  = __float2half(w[f * 256 + src]);
    if (j < 64) {
        int idx = 4 * j + 3;
        ME[f * 64 + j] = (idx < NBINS) ? edges[f * NBINS + idx]      : BIGF;
        MP[f * 64 + j] = (idx < NBINS) ? pair_edges[f * NBINS + idx] : BIGF;
    }
    if (j < 16) {
        CU[f * 16 + j] = (j < 15) ? edges[f * NBINS + 16 * j + 15]      : BIGF;
        CP[f * 16 + j] = (j < 15) ? pair_edges[f * NBINS + 16 * j + 15] : BIGF;
    }
}

// 8-wide vectorized: 262144 threads, each converts 8 elems, 16B uint4 store.
__global__ void ebm_prep_tables(const float* __restrict__ tables,
                                unsigned short* __restrict__ o) {
    int i2 = blockIdx.x * blockDim.x + threadIdx.x;   // 256 blocks x 1024
    int p = i2 >> 13, a = (i2 >> 5) & 255, b0 = (i2 & 31) << 3;
    int ra = (a < 255) ? a + 1 : 0;
    const float* src = tables + (p << 16) + (ra << 8);
    float f[8];
#pragma unroll
    for (int k = 0; k < 8; ++k) {
        int b = b0 + k;
        int rb = (b < 255) ? b + 1 : 0;
        f[k] = src[rb];
    }
    uint4 v;
    v.x = (unsigned)__half_as_ushort(__float2half(f[1])) << 16 |
          (unsigned)__half_as_ushort(__float2half(f[0]));
    v.y = (unsigned)__half_as_ushort(__float2half(f[3])) << 16 |
          (unsigned)__half_as_ushort(__float2half(f[2]));
    v.z = (unsigned)__half_as_ushort(__float2half(f[5])) << 16 |
          (unsigned)__half_as_ushort(__float2half(f[4]));
    v.w = (unsigned)__half_as_ushort(__float2half(f[7])) << 16 |
          (unsigned)__half_as_ushort(__float2half(f[6]));
    *(uint4*)(o + ((size_t)i2 << 3)) = v;
}

// uniform 16-way register select: s is wave-uniform -> 15 v_cndmask w/ scalar masks
__device__ __forceinline__ unsigned pick16(const unsigned* pw, int s) {
    unsigned v01 = (s & 1) ? pw[1]  : pw[0];
    unsigned v23 = (s & 1) ? pw[3]  : pw[2];
    unsigned v45 = (s & 1) ? pw[5]  : pw[4];
    unsigned v67 = (s & 1) ? pw[7]  : pw[6];
    unsigned v89 = (s & 1) ? pw[9]  : pw[8];
    unsigned vab = (s & 1) ? pw[11] : pw[10];
    unsigned vcd = (s & 1) ? pw[13] : pw[12];
    unsigned vef = (s & 1) ? pw[15] : pw[14];
    unsigned w0 = (s & 2) ? v23 : v01;
    unsigned w1 = (s & 2) ? v67 : v45;
    unsigned w2 = (s & 2) ? vab : v89;
    unsigned w3 = (s & 2) ? vef : vcd;
    unsigned u0 = (s & 4) ? w1 : w0;
    unsigned u1 = (s & 4) ? w3 : w2;
    return (s & 8) ? u1 : u0;
}

__global__ __launch_bounds__(1024) void ebm_main(
    const float* __restrict__ x,
    const int*   __restrict__ pairs,
    const float* __restrict__ tables_f32,
    const float* __restrict__ bias,
    const float* __restrict__ ws,
    const __half* __restrict__ T16,
    int useT16,
    float*       __restrict__ out) {

    // 128 KiB: fine tables only, TRANSPOSED section layout (f,k,t)
    __shared__ float sE[16384];
    __shared__ float sPE[16384];

    int tid = threadIdx.x;
    {
        const float4* w4 = (const float4*)ws;
        float4* dE = (float4*)sE;
        float4* dP = (float4*)sPE;
        for (int i = tid; i < 4096; i += 1024) {
            int f = i >> 6, j = i & 63;                 // src float4 j = sect(j>>2), k(j&3)
            int d = (f << 6) + ((j & 3) << 4) + (j >> 2); // dst: f*64 + k*16 + t
            dE[d] = w4[i];
            dP[d] = w4[4096 + i];
        }
    }
    const float*  CU = ws + 40960;
    const float*  CP = ws + 41984;
    const __half* Wg = (const __half*)(ws + 43008);
    float bias0 = bias[0];

    __syncthreads();

    int row = blockIdx.x * 1024 + tid;       // 256 blocks x 1024 threads
    const float4* x4  = (const float4*)x + row * 16;
    const float4* sE4 = (const float4*)sE;
    const float4* sP4 = (const float4*)sPE;

    float acc = 0.f;
    unsigned pw[16];

    float4 xg = x4[0];
#pragma unroll
    for (int g = 0; g < 16; ++g) {
        float4 xnext = xg;
        if (g < 15) xnext = x4[g + 1];
        float xf[4] = {xg.x, xg.y, xg.z, xg.w};
        unsigned pword = 0;

#pragma unroll
        for (int s = 0; s < 2; ++s) {
            float x0 = xf[2 * s], x1 = xf[2 * s + 1];
            int f0 = 4 * g + 2 * s, f1 = f0 + 1;

            // ---- coarse unary (SGPR compares) ----
            int t0 = 0, t1 = 0;
            const float* cu0 = CU + f0 * 16;
            const float* cu1 = CU + f1 * 16;
#pragma unroll
            for (int k = 0; k < 15; ++k) {
                t0 += (x0 >= cu0[k]);
                t1 += (x1 >= cu1[k]);
            }
            // ---- issue 8 unary fine reads (2-way banks, parallel) ----
            float4 a0[4], a1[4];
#pragma unroll
            for (int k = 0; k < 4; ++k) a0[k] = sE4[(f0 << 6) + (k << 4) + t0];
#pragma unroll
            for (int k = 0; k < 4; ++k) a1[k] = sE4[(f1 << 6) + (k << 4) + t1];
            // ---- coarse pair (VALU covers unary read latency) ----
            int u0 = 0, u1 = 0;
            const float* cp0 = CP + f0 * 16;
            const float* cp1 = CP + f1 * 16;
#pragma unroll
            for (int k = 0; k < 15; ++k) {
                u0 += (x0 >= cp0[k]);
                u1 += (x1 >= cp1[k]);
            }
            // ---- consume unary: c = 16t + sum over full section ----
            int c0 = t0 << 4, c1 = t1 << 4;
#pragma unroll
            for (int k = 0; k < 4; ++k) {
                c0 += (x0 >= a0[k].x) + (x0 >= a0[k].y) + (x0 >= a0[k].z) + (x0 >= a0[k].w);
                c1 += (x1 >= a1[k].x) + (x1 >= a1[k].y) + (x1 >= a1[k].z) + (x1 >= a1[k].w);
            }
            acc += __half2float(Wg[f0 * 256 + c0]);     // latency-tolerant
            acc += __half2float(Wg[f1 * 256 + c1]);
            // ---- issue 8 pair fine reads ----
            float4 b0[4], b1[4];
#pragma unroll
            for (int k = 0; k < 4; ++k) b0[k] = sP4[(f0 << 6) + (k << 4) + u0];
#pragma unroll
            for (int k = 0; k < 4; ++k) b1[k] = sP4[(f1 << 6) + (k << 4) + u1];
            // ---- consume pair ----
            int d0 = u0 << 4, d1 = u1 << 4;
#pragma unroll
            for (int k = 0; k < 4; ++k) {
                d0 += (x0 >= b0[k].x) + (x0 >= b0[k].y) + (x0 >= b0[k].z) + (x0 >= b0[k].w);
                d1 += (x1 >= b1[k].x) + (x1 >= b1[k].y) + (x1 >= b1[k].z) + (x1 >= b1[k].w);
            }
            pword |= (unsigned)d0 << (8 * (2 * s));
            pword |= (unsigned)d1 << (8 * (2 * s + 1));
        }
        pw[g] = pword;
        xg = xnext;
    }

    // ---- pair table gathers: per-lane-owned, no exchange ----
    if (useT16) {
#pragma unroll
        for (int p = 0; p < NPAIRS; ++p) {
            int a = pairs[2 * p], b = pairs[2 * p + 1];   // uniform
            unsigned wa = pick16(pw, a >> 2);
            unsigned wb = pick16(pw, b >> 2);
            int li = (wa >> ((a & 3) * 8)) & 255;
            int ri = (wb >> ((b & 3) * 8)) & 255;
            acc += __half2float(T16[(p << 16) + (li << 8) + ri]);
        }
    } else {
#pragma unroll
        for (int p = 0; p < NPAIRS; ++p) {
            int a = pairs[2 * p], b = pairs[2 * p + 1];
            unsigned wa = pick16(pw, a >> 2);
            unsigned wb = pick16(pw, b >> 2);
            int li = (wa >> ((a & 3) * 8)) & 255;
            int ri = (wb >> ((b & 3) * 8)) & 255;
            int lb = (li < 255) ? li + 1 : 0;
            int rb = (ri < 255) ? ri + 1 : 0;
            acc += tables_f32[(p << 16) + (lb << 8) + rb];
        }
    }

    out[row] = 1.0f / (1.0f + __expf(-(acc + bias0)));
}

extern "C" void kernel_launch(void* const* d_in, const int* in_sizes, int n_in,
                              void* d_out, int out_size, void* d_ws, size_t ws_size,
                              hipStream_t stream) {
    const float* x          = (const float*)d_in[0];
    const float* edges      = (const float*)d_in[1];
    const float* w          = (const float*)d_in[2];
    const float* pair_edges = (const float*)d_in[3];
    const int*   pairs      = (const int*)d_in[4];
    const float* tables     = (const float*)d_in[5];
    const float* bias       = (const float*)d_in[6];
    float* out = (float*)d_out;
    float* ws  = (float*)d_ws;

    int useT16 = (ws_size >= (size_t)4399104) ? 1 : 0;
    __half* T16 = (__half*)((char*)d_ws + 204800);

    ebm_prep<<<64, 256, 0, stream>>>(edges, pair_edges, w, ws);
    if (useT16) {
        ebm_prep_tables<<<256, 1024, 0, stream>>>(tables, (unsigned short*)T16);
    }
    ebm_main<<<256, 1024, 0, stream>>>(x, pairs, tables, bias, ws, T16, useT16, out);
}